// Round 1
// baseline (1079.559 us; speedup 1.0000x reference)
//
#include <hip/hip_runtime.h>
#include <hip/hip_bf16.h>

#define N 8192
#define C 256
#define NCLS 1000

typedef __bf16 bf16x8 __attribute__((ext_vector_type(8)));
typedef float floatx4 __attribute__((ext_vector_type(4)));

__device__ __forceinline__ void gload_lds16(const void* g, void* l) {
    __builtin_amdgcn_global_load_lds(
        (const __attribute__((address_space(1))) void*)g,
        (__attribute__((address_space(3))) void*)l, 16, 0, 0);
}

__device__ __forceinline__ unsigned short f2bf(float x) {
    union { float f; unsigned int u; } a; a.f = x;
    unsigned int u = a.u;
    unsigned int r = (u + 0x7fffu + ((u >> 16) & 1u)) >> 16;  // RNE
    return (unsigned short)r;
}

// --- 1. row L2-normalize + cast to bf16 ------------------------------------
__global__ __launch_bounds__(256) void k_norm(const float* __restrict__ f,
                                              unsigned short* __restrict__ fnb) {
    int wid = threadIdx.x >> 6, lane = threadIdx.x & 63;
    int row = blockIdx.x * 4 + wid;
    const float4* fr = (const float4*)(f + (size_t)row * C);
    float4 v = fr[lane];
    float ss = v.x * v.x + v.y * v.y + v.z * v.z + v.w * v.w;
    #pragma unroll
    for (int m = 1; m < 64; m <<= 1) ss += __shfl_xor(ss, m, 64);
    float scale = 1.0f / fmaxf(sqrtf(ss), 1e-8f);
    ushort4 o;
    o.x = f2bf(v.x * scale); o.y = f2bf(v.y * scale);
    o.z = f2bf(v.z * scale); o.w = f2bf(v.w * scale);
    ((ushort4*)(fnb + (size_t)row * C))[lane] = o;
}

// --- 2. class histogram (single block) -------------------------------------
__global__ __launch_bounds__(1024) void k_hist(const int* __restrict__ lab,
                                               int* __restrict__ cnt) {
    __shared__ int bins[NCLS];
    for (int i = threadIdx.x; i < NCLS; i += 1024) bins[i] = 0;
    __syncthreads();
    for (int i = threadIdx.x; i < N; i += 1024) atomicAdd(&bins[lab[i]], 1);
    __syncthreads();
    for (int i = threadIdx.x; i < NCLS; i += 1024) cnt[i] = bins[i];
}

// --- 3. fused symmetric GEMM: upper-triangle blocks, dual-tile epilogue ----
__global__ __launch_bounds__(256) void k_gemm(
    const unsigned short* __restrict__ fnb, const int* __restrict__ lab,
    float* __restrict__ logits, float* __restrict__ perfect,
    float* __restrict__ Ssum, float* __restrict__ Psum) {
    const int bx = blockIdx.x, by = blockIdx.y;
    if (bx < by) return;                 // upper triangle only (colBase >= rowBase)
    const bool diag = (bx == by);

    __shared__ __align__(16) unsigned short As[128 * 32];
    __shared__ __align__(16) unsigned short Bs[128 * 32];
    __shared__ int Lr[128], Lc[128];

    const int t = threadIdx.x;
    const int wid = t >> 6, lane = t & 63;
    const int waveM = wid >> 1, waveN = wid & 1;
    const int quad = lane >> 4, l15 = lane & 15;
    const int rowBase = by * 128;
    const int colBase = bx * 128;

    if (t < 128) Lr[t] = lab[rowBase + t];
    else         Lc[t - 128] = lab[colBase + (t - 128)];

    floatx4 acc[4][4] = {};

    // staging: thread t loads 16B = 8 bf16 ; row = wid*16 + lane/4
    const int srow = wid * 16 + (lane >> 2);
    const int scol = (lane & 3) * 8;
    const unsigned short* gA = fnb + (size_t)(rowBase + srow) * C + scol;
    const unsigned short* gB = fnb + (size_t)(colBase + srow) * C + scol;
    char* asb = (char*)As + wid * 1024;
    char* bsb = (char*)Bs + wid * 1024;

    for (int kb = 0; kb < C; kb += 32) {
        __syncthreads();
        gload_lds16(gA + kb,           asb);
        gload_lds16(gA + kb + 64 * C,  asb + 4096);
        gload_lds16(gB + kb,           bsb);
        gload_lds16(gB + kb + 64 * C,  bsb + 4096);
        __syncthreads();
        bf16x8 a[4], b[4];
        #pragma unroll
        for (int i = 0; i < 4; ++i) {
            a[i] = *(const bf16x8*)&As[(waveM * 64 + i * 16 + l15) * 32 + quad * 8];
            b[i] = *(const bf16x8*)&Bs[(waveN * 64 + i * 16 + l15) * 32 + quad * 8];
        }
        #pragma unroll
        for (int i = 0; i < 4; ++i)
            #pragma unroll
            for (int j = 0; j < 4; ++j)
                acc[i][j] = __builtin_amdgcn_mfma_f32_16x16x32_bf16(a[i], b[j], acc[i][j], 0, 0, 0);
    }

    // epilogue: C/D layout col=lane&15, row=quad*4+reg
    const float invT = 10.0f;
    float colS[4] = {0.f, 0.f, 0.f, 0.f};
    float colP[4] = {0.f, 0.f, 0.f, 0.f};

    #pragma unroll
    for (int i = 0; i < 4; ++i) {
        #pragma unroll
        for (int r = 0; r < 4; ++r) {
            int lrow = waveM * 64 + i * 16 + quad * 4 + r;
            int row = rowBase + lrow;
            int labr = Lr[lrow];
            float eS = 0.f, pS = 0.f;
            #pragma unroll
            for (int j = 0; j < 4; ++j) {
                int lcol = waveN * 64 + j * 16 + l15;
                int col = colBase + lcol;
                float v = acc[i][j][r] * invT;
                size_t off = (size_t)row * N + col;
                bool same = (labr == Lc[lcol]);
                __builtin_nontemporal_store(v, logits + off);
                __builtin_nontemporal_store(same ? 1.0f : -1.0f, perfect + off);
                if (!diag || row != col) {
                    float e = __expf(v);
                    eS += e;
                    if (same) pS += v;
                    if (!diag) {
                        colS[j] += e;
                        if (same) colP[j] += v;
                    }
                }
            }
            #pragma unroll
            for (int m = 1; m < 16; m <<= 1) {
                eS += __shfl_xor(eS, m, 64);
                pS += __shfl_xor(pS, m, 64);
            }
            if (l15 == 0) {
                atomicAdd(&Ssum[row], eS);
                if (pS != 0.0f) atomicAdd(&Psum[row], pS);
            }
        }
    }

    if (!diag) {
        // mirrored tile: logits[col][row] — per-thread regs r=0..3 are 4
        // consecutive columns there -> dwordx4 nontemporal stores
        #pragma unroll
        for (int i = 0; i < 4; ++i) {
            int lr0 = waveM * 64 + i * 16 + quad * 4;
            int tcol0 = rowBase + lr0;
            int la0 = Lr[lr0 + 0], la1 = Lr[lr0 + 1];
            int la2 = Lr[lr0 + 2], la3 = Lr[lr0 + 3];
            #pragma unroll
            for (int j = 0; j < 4; ++j) {
                int lcol = waveN * 64 + j * 16 + l15;
                int trow = colBase + lcol;
                int labc = Lc[lcol];
                floatx4 lv, pv;
                lv[0] = acc[i][j][0] * invT; lv[1] = acc[i][j][1] * invT;
                lv[2] = acc[i][j][2] * invT; lv[3] = acc[i][j][3] * invT;
                pv[0] = (la0 == labc) ? 1.0f : -1.0f;
                pv[1] = (la1 == labc) ? 1.0f : -1.0f;
                pv[2] = (la2 == labc) ? 1.0f : -1.0f;
                pv[3] = (la3 == labc) ? 1.0f : -1.0f;
                size_t off = (size_t)trow * N + tcol0;
                __builtin_nontemporal_store(lv, (floatx4*)(logits + off));
                __builtin_nontemporal_store(pv, (floatx4*)(perfect + off));
            }
        }
        // column-side S/P: reduce over the 4 quads (rows of this wave's half)
        #pragma unroll
        for (int j = 0; j < 4; ++j) {
            float cs = colS[j], cp = colP[j];
            cs += __shfl_xor(cs, 16, 64); cs += __shfl_xor(cs, 32, 64);
            cp += __shfl_xor(cp, 16, 64); cp += __shfl_xor(cp, 32, 64);
            if (quad == 0) {
                int col = colBase + waveN * 64 + j * 16 + l15;
                atomicAdd(&Ssum[col], cs);
                if (cp != 0.0f) atomicAdd(&Psum[col], cp);
            }
        }
    }
}

// --- 4. final loss reduction (single block) --------------------------------
__global__ __launch_bounds__(1024) void k_loss(
    const float* __restrict__ S, const float* __restrict__ P,
    const int* __restrict__ lab, const int* __restrict__ cnt,
    float* __restrict__ out) {
    float sum = 0.f;
    for (int i = threadIdx.x; i < N; i += 1024) {
        float Ki = (float)(cnt[lab[i]] - 1);
        float term = (P[i] - Ki * logf(S[i])) / (Ki + 1e-6f);
        sum += term;
    }
    #pragma unroll
    for (int m = 1; m < 64; m <<= 1) sum += __shfl_xor(sum, m, 64);
    __shared__ float wsum[16];
    int wid = threadIdx.x >> 6, lane = threadIdx.x & 63;
    if (lane == 0) wsum[wid] = sum;
    __syncthreads();
    if (threadIdx.x == 0) {
        float tot = 0.f;
        #pragma unroll
        for (int i = 0; i < 16; ++i) tot += wsum[i];
        out[0] = -tot / (float)N;
    }
}

extern "C" void kernel_launch(void* const* d_in, const int* in_sizes, int n_in,
                              void* d_out, int out_size, void* d_ws, size_t ws_size,
                              hipStream_t stream) {
    const float* f = (const float*)d_in[0];
    const int* lab = (const int*)d_in[1];
    float* out = (float*)d_out;
    float* logits = out + 1;
    float* perfect = out + 1 + (size_t)N * N;

    unsigned short* fnb = (unsigned short*)d_ws;                 // 4 MiB
    float* Ssum = (float*)((char*)d_ws + (size_t)N * C * 2);     // 32 KiB
    float* Psum = Ssum + N;                                      // 32 KiB
    int* cnt = (int*)(Psum + N);                                 // 4 KB

    hipMemsetAsync(Ssum, 0, 2 * N * sizeof(float), stream);
    k_norm<<<N / 4, 256, 0, stream>>>(f, fnb);
    k_hist<<<1, 1024, 0, stream>>>(lab, cnt);
    k_gemm<<<dim3(64, 64), 256, 0, stream>>>(fnb, lab, logits, perfect, Ssum, Psum);
    k_loss<<<1, 1024, 0, stream>>>(Ssum, Psum, lab, cnt, out);
}

// Round 3
// 664.885 us; speedup vs baseline: 1.6237x; 1.6237x over previous
//
#include <hip/hip_runtime.h>
#include <hip/hip_bf16.h>

#define N 8192
#define C 256
#define NCLS 1000

typedef __bf16 bf16x8 __attribute__((ext_vector_type(8)));
typedef float floatx4 __attribute__((ext_vector_type(4)));

__device__ __forceinline__ void gload_lds16(const void* g, void* l) {
    __builtin_amdgcn_global_load_lds(
        (const __attribute__((address_space(1))) void*)g,
        (__attribute__((address_space(3))) void*)l, 16, 0, 0);
}

__device__ __forceinline__ unsigned short f2bf(float x) {
    union { float f; unsigned int u; } a; a.f = x;
    unsigned int u = a.u;
    unsigned int r = (u + 0x7fffu + ((u >> 16) & 1u)) >> 16;  // RNE
    return (unsigned short)r;
}

// --- 1. row L2-normalize + cast to bf16 ------------------------------------
__global__ __launch_bounds__(256) void k_norm(const float* __restrict__ f,
                                              unsigned short* __restrict__ fnb) {
    int wid = threadIdx.x >> 6, lane = threadIdx.x & 63;
    int row = blockIdx.x * 4 + wid;
    const float4* fr = (const float4*)(f + (size_t)row * C);
    float4 v = fr[lane];
    float ss = v.x * v.x + v.y * v.y + v.z * v.z + v.w * v.w;
    #pragma unroll
    for (int m = 1; m < 64; m <<= 1) ss += __shfl_xor(ss, m, 64);
    float scale = 1.0f / fmaxf(sqrtf(ss), 1e-8f);
    ushort4 o;
    o.x = f2bf(v.x * scale); o.y = f2bf(v.y * scale);
    o.z = f2bf(v.z * scale); o.w = f2bf(v.w * scale);
    ((ushort4*)(fnb + (size_t)row * C))[lane] = o;
}

// --- 2. class histogram (single block) -------------------------------------
__global__ __launch_bounds__(1024) void k_hist(const int* __restrict__ lab,
                                               int* __restrict__ cnt) {
    __shared__ int bins[NCLS];
    for (int i = threadIdx.x; i < NCLS; i += 1024) bins[i] = 0;
    __syncthreads();
    for (int i = threadIdx.x; i < N; i += 1024) atomicAdd(&bins[lab[i]], 1);
    __syncthreads();
    for (int i = threadIdx.x; i < NCLS; i += 1024) cnt[i] = bins[i];
}

// --- 3. fused symmetric GEMM: upper-triangle blocks ------------------------
// Mirror tile is transposed through LDS so ALL global stores are coalesced.
__global__ __launch_bounds__(256) void k_gemm(
    const unsigned short* __restrict__ fnb, const int* __restrict__ lab,
    float* __restrict__ logits, float* __restrict__ perfect,
    float* __restrict__ Ssum, float* __restrict__ Psum) {
    const int bx = blockIdx.x, by = blockIdx.y;
    if (bx < by) return;                 // upper triangle only (colBase >= rowBase)
    const bool diag = (bx == by);

    // smem union: K-loop staging (2 x 8 KiB) OR transpose buffer 32x132 f32
    __shared__ __align__(16) char smem[16896];
    unsigned short* As = (unsigned short*)smem;
    unsigned short* Bs = (unsigned short*)(smem + 8192);
    float* T = (float*)smem;             // [32][132], stride 132 breaks bank aliasing
    __shared__ __align__(16) int Lr[128];
    __shared__ __align__(16) int Lc[128];

    const int t = threadIdx.x;
    const int wid = t >> 6, lane = t & 63;
    const int waveM = wid >> 1, waveN = wid & 1;
    const int quad = lane >> 4, l15 = lane & 15;
    const int rowBase = by * 128;
    const int colBase = bx * 128;

    if (t < 128) Lr[t] = lab[rowBase + t];
    else         Lc[t - 128] = lab[colBase + (t - 128)];

    floatx4 acc[4][4] = {};

    // staging: thread t loads 16B = 8 bf16 ; row = wid*16 + lane/4
    const int srow = wid * 16 + (lane >> 2);
    const int scol = (lane & 3) * 8;
    const unsigned short* gA = fnb + (size_t)(rowBase + srow) * C + scol;
    const unsigned short* gB = fnb + (size_t)(colBase + srow) * C + scol;
    char* asb = (char*)As + wid * 1024;
    char* bsb = (char*)Bs + wid * 1024;

    for (int kb = 0; kb < C; kb += 32) {
        __syncthreads();
        gload_lds16(gA + kb,           asb);
        gload_lds16(gA + kb + 64 * C,  asb + 4096);
        gload_lds16(gB + kb,           bsb);
        gload_lds16(gB + kb + 64 * C,  bsb + 4096);
        __syncthreads();
        bf16x8 a[4], b[4];
        #pragma unroll
        for (int i = 0; i < 4; ++i) {
            a[i] = *(const bf16x8*)&As[(waveM * 64 + i * 16 + l15) * 32 + quad * 8];
            b[i] = *(const bf16x8*)&Bs[(waveN * 64 + i * 16 + l15) * 32 + quad * 8];
        }
        #pragma unroll
        for (int i = 0; i < 4; ++i)
            #pragma unroll
            for (int j = 0; j < 4; ++j)
                acc[i][j] = __builtin_amdgcn_mfma_f32_16x16x32_bf16(a[i], b[j], acc[i][j], 0, 0, 0);
    }

    // ---- row-side epilogue: coalesced stores + S/P row and col partials ----
    const float invT = 10.0f;
    float colS[4] = {0.f, 0.f, 0.f, 0.f};
    float colP[4] = {0.f, 0.f, 0.f, 0.f};

    #pragma unroll
    for (int i = 0; i < 4; ++i) {
        #pragma unroll
        for (int r = 0; r < 4; ++r) {
            int lrow = waveM * 64 + i * 16 + quad * 4 + r;
            int row = rowBase + lrow;
            int labr = Lr[lrow];
            float eS = 0.f, pS = 0.f;
            #pragma unroll
            for (int j = 0; j < 4; ++j) {
                int lcol = waveN * 64 + j * 16 + l15;
                int col = colBase + lcol;
                float v = acc[i][j][r] * invT;
                size_t off = (size_t)row * N + col;
                bool same = (labr == Lc[lcol]);
                logits[off] = v;
                perfect[off] = same ? 1.0f : -1.0f;
                if (!diag || row != col) {
                    float e = __expf(v);
                    eS += e;
                    if (same) pS += v;
                    if (!diag) {
                        colS[j] += e;
                        if (same) colP[j] += v;
                    }
                }
            }
            #pragma unroll
            for (int m = 1; m < 16; m <<= 1) {
                eS += __shfl_xor(eS, m, 64);
                pS += __shfl_xor(pS, m, 64);
            }
            if (l15 == 0) {
                atomicAdd(&Ssum[row], eS);
                if (pS != 0.0f) atomicAdd(&Psum[row], pS);
            }
        }
    }

    if (!diag) {
        // column-side S/P: reduce over the 4 quads of this wave's 64 rows
        #pragma unroll
        for (int j = 0; j < 4; ++j) {
            float cs = colS[j], cp = colP[j];
            cs += __shfl_xor(cs, 16, 64); cs += __shfl_xor(cs, 32, 64);
            cp += __shfl_xor(cp, 16, 64); cp += __shfl_xor(cp, 32, 64);
            if (quad == 0) {
                int col = colBase + waveN * 64 + j * 16 + l15;
                atomicAdd(&Ssum[col], cs);
                if (cp != 0.0f) atomicAdd(&Psum[col], cp);
            }
        }

        // ---- mirror tile via LDS transpose: 4 chunks of 32 cols ----
        // chunk c covers tile cols [c*32, c*32+32) -> mirror rows
        #pragma unroll
        for (int c = 0; c < 4; ++c) {
            __syncthreads();             // previous chunk reads (or K-loop) done
            if (waveN == (c >> 1)) {
                #pragma unroll
                for (int jj = 0; jj < 2; ++jj) {
                    int j = (c & 1) * 2 + jj;
                    int tr = jj * 16 + l15;          // row within chunk = lcol - c*32
                    #pragma unroll
                    for (int i = 0; i < 4; ++i) {
                        floatx4 w;
                        w[0] = acc[i][j][0] * invT; w[1] = acc[i][j][1] * invT;
                        w[2] = acc[i][j][2] * invT; w[3] = acc[i][j][3] * invT;
                        *(floatx4*)&T[tr * 132 + waveM * 64 + i * 16 + quad * 4] = w;
                    }
                }
            }
            __syncthreads();
            // cooperative coalesced store: 32 rows x 128 cols
            #pragma unroll
            for (int pass = 0; pass < 4; ++pass) {
                int rr = pass * 8 + (t >> 5);
                int cv = (t & 31) * 4;
                floatx4 lv = *(const floatx4*)&T[rr * 132 + cv];
                int labc = Lc[c * 32 + rr];
                int l0 = Lr[cv + 0], l1 = Lr[cv + 1];
                int l2 = Lr[cv + 2], l3 = Lr[cv + 3];
                floatx4 pv;
                pv[0] = (l0 == labc) ? 1.0f : -1.0f;
                pv[1] = (l1 == labc) ? 1.0f : -1.0f;
                pv[2] = (l2 == labc) ? 1.0f : -1.0f;
                pv[3] = (l3 == labc) ? 1.0f : -1.0f;
                size_t off = (size_t)(colBase + c * 32 + rr) * N + rowBase + cv;
                *(floatx4*)(logits + off) = lv;
                *(floatx4*)(perfect + off) = pv;
            }
        }
    }
}

// --- 4. final loss reduction (single block) --------------------------------
__global__ __launch_bounds__(1024) void k_loss(
    const float* __restrict__ S, const float* __restrict__ P,
    const int* __restrict__ lab, const int* __restrict__ cnt,
    float* __restrict__ out) {
    float sum = 0.f;
    for (int i = threadIdx.x; i < N; i += 1024) {
        float Ki = (float)(cnt[lab[i]] - 1);
        float term = (P[i] - Ki * logf(S[i])) / (Ki + 1e-6f);
        sum += term;
    }
    #pragma unroll
    for (int m = 1; m < 64; m <<= 1) sum += __shfl_xor(sum, m, 64);
    __shared__ float wsum[16];
    int wid = threadIdx.x >> 6, lane = threadIdx.x & 63;
    if (lane == 0) wsum[wid] = sum;
    __syncthreads();
    if (threadIdx.x == 0) {
        float tot = 0.f;
        #pragma unroll
        for (int i = 0; i < 16; ++i) tot += wsum[i];
        out[0] = -tot / (float)N;
    }
}

extern "C" void kernel_launch(void* const* d_in, const int* in_sizes, int n_in,
                              void* d_out, int out_size, void* d_ws, size_t ws_size,
                              hipStream_t stream) {
    const float* f = (const float*)d_in[0];
    const int* lab = (const int*)d_in[1];
    float* out = (float*)d_out;
    float* logits = out + 1;
    float* perfect = out + 1 + (size_t)N * N;

    unsigned short* fnb = (unsigned short*)d_ws;                 // 4 MiB
    float* Ssum = (float*)((char*)d_ws + (size_t)N * C * 2);     // 32 KiB
    float* Psum = Ssum + N;                                      // 32 KiB
    int* cnt = (int*)(Psum + N);                                 // 4 KB

    hipMemsetAsync(Ssum, 0, 2 * N * sizeof(float), stream);
    k_norm<<<N / 4, 256, 0, stream>>>(f, fnb);
    k_hist<<<1, 1024, 0, stream>>>(lab, cnt);
    k_gemm<<<dim3(64, 64), 256, 0, stream>>>(fnb, lab, logits, perfect, Ssum, Psum);
    k_loss<<<1, 1024, 0, stream>>>(Ssum, Psum, lab, cnt, out);
}

// Round 4
// 626.441 us; speedup vs baseline: 1.7233x; 1.0614x over previous
//
#include <hip/hip_runtime.h>
#include <hip/hip_bf16.h>

#define N 8192
#define C 256
#define NCLS 1000

typedef __bf16 bf16x8 __attribute__((ext_vector_type(8)));
typedef float floatx4 __attribute__((ext_vector_type(4)));

__device__ __forceinline__ void gload_lds16(const void* g, void* l) {
    __builtin_amdgcn_global_load_lds(
        (const __attribute__((address_space(1))) void*)g,
        (__attribute__((address_space(3))) void*)l, 16, 0, 0);
}

__device__ __forceinline__ unsigned short f2bf(float x) {
    union { float f; unsigned int u; } a; a.f = x;
    unsigned int u = a.u;
    unsigned int r = (u + 0x7fffu + ((u >> 16) & 1u)) >> 16;  // RNE
    return (unsigned short)r;
}

// --- 1. row L2-normalize + cast to bf16 ------------------------------------
__global__ __launch_bounds__(256) void k_norm(const float* __restrict__ f,
                                              unsigned short* __restrict__ fnb) {
    int wid = threadIdx.x >> 6, lane = threadIdx.x & 63;
    int row = blockIdx.x * 4 + wid;
    const float4* fr = (const float4*)(f + (size_t)row * C);
    float4 v = fr[lane];
    float ss = v.x * v.x + v.y * v.y + v.z * v.z + v.w * v.w;
    #pragma unroll
    for (int m = 1; m < 64; m <<= 1) ss += __shfl_xor(ss, m, 64);
    float scale = 1.0f / fmaxf(sqrtf(ss), 1e-8f);
    ushort4 o;
    o.x = f2bf(v.x * scale); o.y = f2bf(v.y * scale);
    o.z = f2bf(v.z * scale); o.w = f2bf(v.w * scale);
    ((ushort4*)(fnb + (size_t)row * C))[lane] = o;
}

// --- 2. class histogram (single block) -------------------------------------
__global__ __launch_bounds__(1024) void k_hist(const int* __restrict__ lab,
                                               int* __restrict__ cnt) {
    __shared__ int bins[NCLS];
    for (int i = threadIdx.x; i < NCLS; i += 1024) bins[i] = 0;
    __syncthreads();
    for (int i = threadIdx.x; i < N; i += 1024) atomicAdd(&bins[lab[i]], 1);
    __syncthreads();
    for (int i = threadIdx.x; i < NCLS; i += 1024) cnt[i] = bins[i];
}

// --- 2b. perfect_logit: pure streaming label-compare writer ----------------
// Linear float4 row sweeps (fill-kernel access shape) -> near-HBM-peak BW.
__global__ __launch_bounds__(256) void k_perfect(const int* __restrict__ lab,
                                                 float* __restrict__ perfect) {
    __shared__ int labs[N];   // 32 KiB
    const int t = threadIdx.x;
    #pragma unroll
    for (int p = 0; p < N / (256 * 4); ++p) {
        int idx = (p * 256 + t) * 4;
        int4 v = *(const int4*)(lab + idx);
        *(int4*)&labs[idx] = v;
    }
    __syncthreads();
    int row0 = blockIdx.x * 4;
    #pragma unroll
    for (int rr = 0; rr < 4; ++rr) {
        int row = row0 + rr;
        int lr = labs[row];
        float* dst = perfect + (size_t)row * N;
        #pragma unroll
        for (int p = 0; p < 8; ++p) {
            int c = (p * 256 + t) * 4;
            floatx4 pv;
            pv[0] = (labs[c + 0] == lr) ? 1.0f : -1.0f;
            pv[1] = (labs[c + 1] == lr) ? 1.0f : -1.0f;
            pv[2] = (labs[c + 2] == lr) ? 1.0f : -1.0f;
            pv[3] = (labs[c + 3] == lr) ? 1.0f : -1.0f;
            *(floatx4*)(dst + c) = pv;
        }
    }
}

// --- 3. fused symmetric GEMM: upper-triangle blocks, logits only -----------
// Mirror tile is transposed through LDS so ALL global stores are coalesced.
__global__ __launch_bounds__(256) void k_gemm(
    const unsigned short* __restrict__ fnb, const int* __restrict__ lab,
    float* __restrict__ logits,
    float* __restrict__ Ssum, float* __restrict__ Psum) {
    const int bx = blockIdx.x, by = blockIdx.y;
    if (bx < by) return;                 // upper triangle only (colBase >= rowBase)
    const bool diag = (bx == by);

    // smem union: K-loop staging (2 x 8 KiB) OR transpose buffer 32x132 f32
    __shared__ __align__(16) char smem[16896];
    unsigned short* As = (unsigned short*)smem;
    unsigned short* Bs = (unsigned short*)(smem + 8192);
    float* T = (float*)smem;             // [32][132], stride 132 breaks bank aliasing
    __shared__ __align__(16) int Lr[128];
    __shared__ __align__(16) int Lc[128];

    const int t = threadIdx.x;
    const int wid = t >> 6, lane = t & 63;
    const int waveM = wid >> 1, waveN = wid & 1;
    const int quad = lane >> 4, l15 = lane & 15;
    const int rowBase = by * 128;
    const int colBase = bx * 128;

    if (t < 128) Lr[t] = lab[rowBase + t];
    else         Lc[t - 128] = lab[colBase + (t - 128)];

    floatx4 acc[4][4] = {};

    // staging: thread t loads 16B = 8 bf16 ; row = wid*16 + lane/4
    const int srow = wid * 16 + (lane >> 2);
    const int scol = (lane & 3) * 8;
    const unsigned short* gA = fnb + (size_t)(rowBase + srow) * C + scol;
    const unsigned short* gB = fnb + (size_t)(colBase + srow) * C + scol;
    char* asb = (char*)As + wid * 1024;
    char* bsb = (char*)Bs + wid * 1024;

    for (int kb = 0; kb < C; kb += 32) {
        __syncthreads();
        gload_lds16(gA + kb,           asb);
        gload_lds16(gA + kb + 64 * C,  asb + 4096);
        gload_lds16(gB + kb,           bsb);
        gload_lds16(gB + kb + 64 * C,  bsb + 4096);
        __syncthreads();
        bf16x8 a[4], b[4];
        #pragma unroll
        for (int i = 0; i < 4; ++i) {
            a[i] = *(const bf16x8*)&As[(waveM * 64 + i * 16 + l15) * 32 + quad * 8];
            b[i] = *(const bf16x8*)&Bs[(waveN * 64 + i * 16 + l15) * 32 + quad * 8];
        }
        #pragma unroll
        for (int i = 0; i < 4; ++i)
            #pragma unroll
            for (int j = 0; j < 4; ++j)
                acc[i][j] = __builtin_amdgcn_mfma_f32_16x16x32_bf16(a[i], b[j], acc[i][j], 0, 0, 0);
    }

    // ---- row-side epilogue: logits stores + S/P row and col partials ----
    const float invT = 10.0f;
    float colS[4] = {0.f, 0.f, 0.f, 0.f};
    float colP[4] = {0.f, 0.f, 0.f, 0.f};

    #pragma unroll
    for (int i = 0; i < 4; ++i) {
        #pragma unroll
        for (int r = 0; r < 4; ++r) {
            int lrow = waveM * 64 + i * 16 + quad * 4 + r;
            int row = rowBase + lrow;
            int labr = Lr[lrow];
            float eS = 0.f, pS = 0.f;
            #pragma unroll
            for (int j = 0; j < 4; ++j) {
                int lcol = waveN * 64 + j * 16 + l15;
                int col = colBase + lcol;
                float v = acc[i][j][r] * invT;
                size_t off = (size_t)row * N + col;
                bool same = (labr == Lc[lcol]);
                logits[off] = v;
                if (!diag || row != col) {
                    float e = __expf(v);
                    eS += e;
                    if (same) pS += v;
                    if (!diag) {
                        colS[j] += e;
                        if (same) colP[j] += v;
                    }
                }
            }
            #pragma unroll
            for (int m = 1; m < 16; m <<= 1) {
                eS += __shfl_xor(eS, m, 64);
                pS += __shfl_xor(pS, m, 64);
            }
            if (l15 == 0) {
                atomicAdd(&Ssum[row], eS);
                if (pS != 0.0f) atomicAdd(&Psum[row], pS);
            }
        }
    }

    if (!diag) {
        // column-side S/P: reduce over the 4 quads of this wave's 64 rows
        #pragma unroll
        for (int j = 0; j < 4; ++j) {
            float cs = colS[j], cp = colP[j];
            cs += __shfl_xor(cs, 16, 64); cs += __shfl_xor(cs, 32, 64);
            cp += __shfl_xor(cp, 16, 64); cp += __shfl_xor(cp, 32, 64);
            if (quad == 0) {
                int col = colBase + waveN * 64 + j * 16 + l15;
                atomicAdd(&Ssum[col], cs);
                if (cp != 0.0f) atomicAdd(&Psum[col], cp);
            }
        }

        // ---- mirror tile via LDS transpose: 4 chunks of 32 cols ----
        #pragma unroll
        for (int c = 0; c < 4; ++c) {
            __syncthreads();             // previous chunk reads (or K-loop) done
            if (waveN == (c >> 1)) {
                #pragma unroll
                for (int jj = 0; jj < 2; ++jj) {
                    int j = (c & 1) * 2 + jj;
                    int tr = jj * 16 + l15;          // row within chunk = lcol - c*32
                    #pragma unroll
                    for (int i = 0; i < 4; ++i) {
                        floatx4 w;
                        w[0] = acc[i][j][0] * invT; w[1] = acc[i][j][1] * invT;
                        w[2] = acc[i][j][2] * invT; w[3] = acc[i][j][3] * invT;
                        *(floatx4*)&T[tr * 132 + waveM * 64 + i * 16 + quad * 4] = w;
                    }
                }
            }
            __syncthreads();
            // cooperative coalesced store: 32 rows x 128 cols
            #pragma unroll
            for (int pass = 0; pass < 4; ++pass) {
                int rr = pass * 8 + (t >> 5);
                int cv = (t & 31) * 4;
                floatx4 lv = *(const floatx4*)&T[rr * 132 + cv];
                size_t off = (size_t)(colBase + c * 32 + rr) * N + rowBase + cv;
                *(floatx4*)(logits + off) = lv;
            }
        }
    }
}

// --- 4. final loss reduction (single block) --------------------------------
__global__ __launch_bounds__(1024) void k_loss(
    const float* __restrict__ S, const float* __restrict__ P,
    const int* __restrict__ lab, const int* __restrict__ cnt,
    float* __restrict__ out) {
    float sum = 0.f;
    for (int i = threadIdx.x; i < N; i += 1024) {
        float Ki = (float)(cnt[lab[i]] - 1);
        float term = (P[i] - Ki * logf(S[i])) / (Ki + 1e-6f);
        sum += term;
    }
    #pragma unroll
    for (int m = 1; m < 64; m <<= 1) sum += __shfl_xor(sum, m, 64);
    __shared__ float wsum[16];
    int wid = threadIdx.x >> 6, lane = threadIdx.x & 63;
    if (lane == 0) wsum[wid] = sum;
    __syncthreads();
    if (threadIdx.x == 0) {
        float tot = 0.f;
        #pragma unroll
        for (int i = 0; i < 16; ++i) tot += wsum[i];
        out[0] = -tot / (float)N;
    }
}

extern "C" void kernel_launch(void* const* d_in, const int* in_sizes, int n_in,
                              void* d_out, int out_size, void* d_ws, size_t ws_size,
                              hipStream_t stream) {
    const float* f = (const float*)d_in[0];
    const int* lab = (const int*)d_in[1];
    float* out = (float*)d_out;
    float* logits = out + 1;
    float* perfect = out + 1 + (size_t)N * N;

    unsigned short* fnb = (unsigned short*)d_ws;                 // 4 MiB
    float* Ssum = (float*)((char*)d_ws + (size_t)N * C * 2);     // 32 KiB
    float* Psum = Ssum + N;                                      // 32 KiB
    int* cnt = (int*)(Psum + N);                                 // 4 KB

    hipMemsetAsync(Ssum, 0, 2 * N * sizeof(float), stream);
    k_perfect<<<N / 4, 256, 0, stream>>>(lab, perfect);
    k_norm<<<N / 4, 256, 0, stream>>>(f, fnb);
    k_hist<<<1, 1024, 0, stream>>>(lab, cnt);
    k_gemm<<<dim3(64, 64), 256, 0, stream>>>(fnb, lab, logits, Ssum, Psum);
    k_loss<<<1, 1024, 0, stream>>>(Ssum, Psum, lab, cnt, out);
}